// Round 12
// baseline (166.017 us; speedup 1.0000x reference)
//
#include <hip/hip_runtime.h>
#include <math.h>

#define HIDN 512
#define PROJ 1024
#define ATTN 128
#define BATCH 4
#define SEQ 2048
#define N1 (2*PROJ+ATTN)      // 2176
#define ROWS (BATCH*SEQ)      // 8192
#define QR 16                 // q-rows per qksm block

typedef __attribute__((ext_vector_type(4))) float f32x4;
typedef __attribute__((ext_vector_type(8))) short bf16x8;

// bf16 <-> f32 via bit ops (round-to-nearest-even), no header dependency
__device__ __forceinline__ short f2bf(float x){
    unsigned u = __builtin_bit_cast(unsigned, x);
    unsigned rounding = 0x7fffu + ((u >> 16) & 1u);
    u += rounding;
    return (short)(u >> 16);
}
__device__ __forceinline__ float bf2f(short s){
    unsigned u = ((unsigned)(unsigned short)s) << 16;
    return __builtin_bit_cast(float, u);
}

__device__ __forceinline__ void gload16(const void* g, void* l){
    __builtin_amdgcn_global_load_lds((const __attribute__((address_space(1))) void*)g,
                                     (__attribute__((address_space(3))) void*)l,
                                     16, 0, 0);
}

// ---------------- double-buffered bt-GEMM tile: C[128x128] = A[M][K] @ BT[N][K]^T
// 256 threads (4 waves, 2x2), 16x16x32 bf16 MFMA. T3 minimum-2-phase + T2 swizzle.
template<int BK, class Epi>
__device__ __forceinline__ void gemm_bt_tile(const short* __restrict__ A, int lda,
                                             const short* __restrict__ BT, int ldb,
                                             int m0, int n0, int K, Epi epi)
{
    __shared__ __align__(16) short lA[2][128*BK];
    __shared__ __align__(16) short lB[2][128*BK];
    const int t = threadIdx.x;
    const int lane = t & 63;
    const int w = t >> 6;
    const int wr = (w >> 1) * 64, wc = (w & 1) * 64;
    const int half = lane >> 4, l16 = lane & 15;
    constexpr int SPT = BK/16;            // bf16x8 loads per thread per matrix

    f32x4 acc[4][4];
    #pragma unroll
    for (int i=0;i<4;i++)
        #pragma unroll
        for (int j=0;j<4;j++)
            acc[i][j] = (f32x4){0.f,0.f,0.f,0.f};

    auto stage = [&](int buf, int k0){
        #pragma unroll
        for (int i = 0; i < SPT; i++) {
            int li = i*256 + t;
            int r = li / (BK/8), s = li % (BK/8);
            int ss = (BK==64) ? (s ^ (r & 7)) : (s ^ ((r >> 1) & 3));
            gload16(A + (size_t)(m0+r)*lda + k0 + ss*8, lA[buf] + li*8);
        }
        #pragma unroll
        for (int i = 0; i < SPT; i++) {
            int li = i*256 + t;
            int r = li / (BK/8), s = li % (BK/8);
            int ss = (BK==64) ? (s ^ (r & 7)) : (s ^ ((r >> 1) & 3));
            gload16(BT + (size_t)(n0+r)*ldb + k0 + ss*8, lB[buf] + li*8);
        }
    };

    stage(0, 0);
    __syncthreads();
    int cur = 0;
    for (int k0 = BK; k0 <= K; k0 += BK) {
        if (k0 < K) stage(cur^1, k0);             // prefetch next tile during MFMA
        #pragma unroll
        for (int kk = 0; kk < BK; kk += 32) {
            bf16x8 af[4], bfr[4];
            const int cs = (kk >> 3) + half;
            #pragma unroll
            for (int i=0;i<4;i++){
                int row = wr + i*16 + l16;
                int sl = (BK==64) ? (cs ^ (row & 7)) : (cs ^ ((row >> 1) & 3));
                af[i] = *(const bf16x8*)(lA[cur] + row*BK + sl*8);
            }
            #pragma unroll
            for (int j=0;j<4;j++){
                int row = wc + j*16 + l16;
                int sl = (BK==64) ? (cs ^ (row & 7)) : (cs ^ ((row >> 1) & 3));
                bfr[j] = *(const bf16x8*)(lB[cur] + row*BK + sl*8);
            }
            #pragma unroll
            for (int i=0;i<4;i++)
                #pragma unroll
                for (int j=0;j<4;j++)
                    acc[i][j] = __builtin_amdgcn_mfma_f32_16x16x32_bf16(af[i], bfr[j], acc[i][j], 0, 0, 0);
        }
        __syncthreads();
        cur ^= 1;
    }
    // C/D layout: col = lane&15, row = (lane>>4)*4 + q   [m89/m91 verified]
    #pragma unroll
    for (int i=0;i<4;i++)
        #pragma unroll
        for (int j=0;j<4;j++)
            #pragma unroll
            for (int q=0;q<4;q++)
                epi(m0 + wr + i*16 + half*4 + q, n0 + wc + j*16 + l16, acc[i][j][q]);
}

// ---------------- helpers ----------------
__global__ void k_cast_node(const float* __restrict__ in, short* __restrict__ out){
    int idx = blockIdx.x*256 + threadIdx.x;
    const float4 v = ((const float4*)in)[idx];
    short4 o; o.x = f2bf(v.x); o.y = f2bf(v.y); o.z = f2bf(v.z); o.w = f2bf(v.w);
    ((short4*)out)[idx] = o;
}

__global__ void k_transpose_cast(const float* __restrict__ in, short* __restrict__ out,
                                 int R, int C){
    __shared__ short tile[64][65];
    int r0 = blockIdx.y*64, c0 = blockIdx.x*64;
    int t = threadIdx.x;
    #pragma unroll
    for (int i=0;i<16;i++){
        int lin = i*256 + t; int r = lin>>6, c = lin&63;
        tile[r][c] = f2bf(in[(size_t)(r0+r)*C + c0+c]);
    }
    __syncthreads();
    #pragma unroll
    for (int i=0;i<16;i++){
        int lin = i*256 + t; int c = lin>>6, r = lin&63;
        out[(size_t)(c0+c)*R + r0+r] = tile[r][c];
    }
}

__global__ void k_transpose_v(const short* __restrict__ values, short* __restrict__ VT){
    __shared__ short tile[64][65];
    int z = blockIdx.z;
    int c0 = blockIdx.x*64, r0 = blockIdx.y*64;
    int t = threadIdx.x;
    #pragma unroll
    for (int i=0;i<16;i++){
        int lin = i*256 + t; int r = lin>>6, c = lin&63;
        tile[r][c] = values[(size_t)(z*SEQ + r0+r)*PROJ + c0+c];
    }
    __syncthreads();
    #pragma unroll
    for (int i=0;i<16;i++){
        int lin = i*256 + t; int c = lin>>6, r = lin&63;
        VT[((size_t)z*PROJ + c0+c)*SEQ + r0+r] = tile[r][c];
    }
}

// ---------------- GEMM1: silu(node@w1+b1) -> gates/values/base (bf16), BK=32
__global__ __launch_bounds__(256) void k_mm1(const short* __restrict__ nodeb,
        const short* __restrict__ w1T, const float* __restrict__ b1,
        short* __restrict__ gates, short* __restrict__ values, short* __restrict__ baseb){
    int b = blockIdx.x;
    int wg = (b & 7) * (N1/128*64/8) + (b >> 3);   // cpx = 136
    int n0 = (wg % (N1/128))*128, m0 = (wg / (N1/128))*128;
    gemm_bt_tile<32>(nodeb, HIDN, w1T, HIDN, m0, n0, HIDN,
        [=](int row, int col, float v){
            v += b1[col];
            v = v / (1.f + __expf(-v));
            short bv = f2bf(v);
            if (col < PROJ)        gates [(size_t)row*PROJ + col]        = bv;
            else if (col < 2*PROJ) values[(size_t)row*PROJ + col-PROJ]   = bv;
            else                   baseb [(size_t)row*ATTN + col-2*PROJ] = bv;
        });
}

// ---------------- RoPE
__global__ void k_rope2(const short* __restrict__ baseb, const float* __restrict__ msw,
                        const float* __restrict__ msb, const float* __restrict__ scaling,
                        short* __restrict__ qb, short* __restrict__ kb){
    int idx = blockIdx.x*256 + threadIdx.x;
    int d = idx & 63;
    int row = idx >> 6;
    int l = row & (SEQ-1);
    float inv = exp2f(-(float)d * (13.287712379549449f/64.f));
    float ang = (float)l * inv;
    float s = sinf(ang), c = cosf(ang);
    const short* bp = baseb + (size_t)row*ATTN;
    float b_lo = bf2f(bp[d]), b_hi = bf2f(bp[d+64]);
    float x1q = b_lo*msw[d]        + msb[d];
    float x2q = b_hi*msw[d+64]     + msb[d+64];
    float x1k = b_lo*msw[128+d]    + msb[128+d];
    float x2k = b_hi*msw[128+d+64] + msb[128+d+64];
    float sc = scaling[0];
    qb[(size_t)row*ATTN + d]    = f2bf((x1q*c - x2q*s)*sc);
    qb[(size_t)row*ATTN + d+64] = f2bf((x2q*c + x1q*s)*sc);
    kb[(size_t)row*ATTN + d]    = f2bf(x1k*c - x2k*s);
    kb[(size_t)row*ATTN + d+64] = f2bf(x2k*c + x1k*s);
}

// ---------------- QK^T + bias + exp -> UNNORMALIZED bf16 P~ + partial rowsums.
// v6 = R11's barrier-free structure + kv-SPLIT: blockIdx.z picks a 1024-kv half;
// grid 1024 blocks -> 4 blocks/CU (100% occupancy headroom), serial chain halves.
// Partial sums go to lsum[kvh][row]; pv2 epilogue combines.
__global__ __launch_bounds__(512, 4) void k_qksm(
        const short* __restrict__ qg, const short* __restrict__ kg,
        const float* __restrict__ bias, short* __restrict__ P,
        float* __restrict__ lsum)
{
    __shared__ short ptw[8][16][56];     // wave-private transpose patch (14KB)
    __shared__ float s_l[8][16];

    const int z = blockIdx.y;
    const int r0 = blockIdx.x * QR;
    const int kvh = blockIdx.z;          // 0/1: which 1024-kv half
    const int kv0 = kvh * 1024;
    const int t = threadIdx.x;
    const int w = t >> 6;                // 0..7
    const int lane = t & 63;
    const int l16 = lane & 15, half = lane >> 4;

    const short* Q  = qg + ((size_t)z*SEQ + r0)*ATTN;
    const short* K  = kg + (size_t)z*SEQ*ATTN;
    const float* Bb = bias + ((size_t)z*SEQ + r0)*SEQ;
    short* Pp = P + ((size_t)z*SEQ + r0)*SEQ;

    // Q A-frags: row = l16 (q), k = kc*32 + half*8
    bf16x8 qf[4];
    #pragma unroll
    for (int kc=0;kc<4;kc++)
        qf[kc] = *(const bf16x8*)(Q + (size_t)l16*ATTN + kc*32 + half*8);

    f32x4 ts = (f32x4){0.f,0.f,0.f,0.f};   // row-sum partials for q=half*4+e

    // bias prefetch for chunk 0
    float bn[2][4];
    #pragma unroll
    for (int j=0;j<2;j++)
        #pragma unroll
        for (int e=0;e<4;e++)
            bn[j][e] = Bb[(size_t)(half*4+e)*SEQ + kv0 + w*32 + j*16 + l16];

    #pragma unroll 2
    for (int c=0; c<4; c++){
        float bx[2][4];
        if (c < 3){
            #pragma unroll
            for (int j=0;j<2;j++)
                #pragma unroll
                for (int e=0;e<4;e++)
                    bx[j][e] = Bb[(size_t)(half*4+e)*SEQ + kv0 + (c+1)*256 + w*32 + j*16 + l16];
        }
        // compute 2 tiles: S = Q.K^T with acc seeded by bias
        #pragma unroll
        for (int j=0;j<2;j++){
            const int kvb = kv0 + c*256 + w*32 + j*16;
            const short* Kc = K + (size_t)(kvb + l16)*ATTN;
            f32x4 a = (f32x4){bn[j][0], bn[j][1], bn[j][2], bn[j][3]};
            #pragma unroll
            for (int kc=0;kc<4;kc++){
                bf16x8 kf = *(const bf16x8*)(Kc + kc*32 + half*8);
                a = __builtin_amdgcn_mfma_f32_16x16x32_bf16(qf[kc], kf, a, 0,0,0);
            }
            float p0 = __expf(a[0]), p1 = __expf(a[1]);
            float p2 = __expf(a[2]), p3 = __expf(a[3]);
            ts[0] += p0; ts[1] += p1; ts[2] += p2; ts[3] += p3;
            ptw[w][half*4+0][j*16+l16] = f2bf(p0);
            ptw[w][half*4+1][j*16+l16] = f2bf(p1);
            ptw[w][half*4+2][j*16+l16] = f2bf(p2);
            ptw[w][half*4+3][j*16+l16] = f2bf(p3);
        }
        // wave-private transpose-out: lane reads row=lane>>2, 8 cols at (lane&3)*8
        {
            bf16x8 v = *(const bf16x8*)&ptw[w][lane>>2][(lane&3)*8];
            *(bf16x8*)(Pp + (size_t)(lane>>2)*SEQ + kv0 + c*256 + w*32 + (lane&3)*8) = v;
        }
        #pragma unroll
        for (int j=0;j<2;j++)
            #pragma unroll
            for (int e=0;e<4;e++)
                bn[j][e] = bx[j][e];
    }

    // partial row-sum reduce over l16 (cols), then across 8 waves via LDS
    #pragma unroll
    for (int e=0;e<4;e++){
        ts[e] += __shfl_xor(ts[e],1,64);
        ts[e] += __shfl_xor(ts[e],2,64);
        ts[e] += __shfl_xor(ts[e],4,64);
        ts[e] += __shfl_xor(ts[e],8,64);
    }
    if (l16 == 0){
        #pragma unroll
        for (int e=0;e<4;e++) s_l[w][half*4+e] = ts[e];
    }
    __syncthreads();
    if (t < 16){
        float sum = 0.f;
        #pragma unroll
        for (int ww=0; ww<8; ww++) sum += s_l[ww][t];
        lsum[(size_t)kvh*ROWS + (size_t)z*SEQ + r0 + t] = sum;
    }
}

// ---------------- PV: a2 = (P~ @ V) / (s0+s1) * gates  (bf16 out), BK=64
__global__ __launch_bounds__(256) void k_pv2(const short* __restrict__ P,
        const short* __restrict__ VT, const short* __restrict__ gates,
        const float* __restrict__ lsum, short* __restrict__ a2){
    int b = blockIdx.x;
    int wg = (b & 7) * 64 + (b >> 3);
    int xx = wg & 7, yy = (wg >> 3) & 15, z = wg >> 7;
    const short* A = P  + (size_t)z*SEQ*SEQ;
    const short* B = VT + (size_t)z*PROJ*SEQ;
    int n0 = xx*128, m0 = yy*128;
    gemm_bt_tile<64>(A, SEQ, B, SEQ, m0, n0, SEQ,
        [=](int r, int c, float v){
            size_t ri = (size_t)z*SEQ + r;
            float li = 1.f / (lsum[ri] + lsum[(size_t)ROWS + ri]);
            size_t gi = ri*PROJ + c;
            a2[gi] = f2bf(v * li * bf2f(gates[gi]));
        });
}

// ---------------- GEMM2: out = a2 @ w2 + b2  (f32 out), BK=32
__global__ __launch_bounds__(256) void k_mm2(const short* __restrict__ a2,
        const short* __restrict__ w2T, const float* __restrict__ b2,
        float* __restrict__ out){
    int b = blockIdx.x;
    int wg = (b & 7) * 32 + (b >> 3);
    int n0 = (wg & 3)*128, m0 = (wg >> 2)*128;
    gemm_bt_tile<32>(a2, PROJ, w2T, PROJ, m0, n0, PROJ,
        [=](int r, int c, float v){
            out[(size_t)r*HIDN + c] = v + b2[c];
        });
}

extern "C" void kernel_launch(void* const* d_in, const int* in_sizes, int n_in,
                              void* d_out, int out_size, void* d_ws, size_t ws_size,
                              hipStream_t stream) {
    const float* node    = (const float*)d_in[0];
    const float* bias    = (const float*)d_in[1];
    const float* scaling = (const float*)d_in[2];
    const float* w1      = (const float*)d_in[3];
    const float* b1      = (const float*)d_in[4];
    const float* msw     = (const float*)d_in[5];
    const float* msb     = (const float*)d_in[6];
    const float* w2      = (const float*)d_in[7];
    const float* b2      = (const float*)d_in[8];
    float* out = (float*)d_out;

    char* p = (char*)d_ws;
    auto alloc = [&](size_t bytes){ char* r = p; p += (bytes + 255) & ~(size_t)255; return r; };
    short* nodeb  = (short*)alloc((size_t)ROWS*HIDN*2);
    short* w1T    = (short*)alloc((size_t)N1*HIDN*2);
    short* w2T    = (short*)alloc((size_t)HIDN*PROJ*2);
    short* gates  = (short*)alloc((size_t)ROWS*PROJ*2);
    short* values = (short*)alloc((size_t)ROWS*PROJ*2);
    short* VT     = (short*)alloc((size_t)BATCH*PROJ*SEQ*2);
    short* baseb  = (short*)alloc((size_t)ROWS*ATTN*2);
    short* qb     = (short*)alloc((size_t)ROWS*ATTN*2);
    short* kb     = (short*)alloc((size_t)ROWS*ATTN*2);
    short* Pbuf   = (short*)alloc((size_t)BATCH*SEQ*SEQ*2);
    float* lsum   = (float*)alloc((size_t)2*ROWS*4);
    short* a2buf  = (short*)alloc((size_t)ROWS*PROJ*2);

    k_cast_node<<<ROWS*HIDN/1024, 256, 0, stream>>>(node, nodeb);
    k_transpose_cast<<<dim3(N1/64, HIDN/64), 256, 0, stream>>>(w1, w1T, HIDN, N1);
    k_transpose_cast<<<dim3(HIDN/64, PROJ/64), 256, 0, stream>>>(w2, w2T, PROJ, HIDN);
    // 1) gva = silu(node@w1+b1)
    k_mm1<<<(N1/128)*(ROWS/128), 256, 0, stream>>>(nodeb, w1T, b1, gates, values, baseb);
    // transpose values for PV B^T layout
    k_transpose_v<<<dim3(PROJ/64, SEQ/64, BATCH), 256, 0, stream>>>(values, VT);
    // 2) rope
    k_rope2<<<ROWS*64/256, 256, 0, stream>>>(baseb, msw, msb, scaling, qb, kb);
    // 3) barrier-free streaming qk^T + bias + exp -> P~ + partial sums (kv-split x2)
    k_qksm<<<dim3(SEQ/QR, BATCH, 2), 512, 0, stream>>>(qb, kb, bias, Pbuf, lsum);
    // 3c) a2 = (P~@V)/(s0+s1)*gates
    k_pv2<<<(PROJ/128)*(SEQ/128)*BATCH, 256, 0, stream>>>(Pbuf, VT, gates, lsum, a2buf);
    // 4) out = a2@w2 + b2
    k_mm2<<<(HIDN/128)*(ROWS/128), 256, 0, stream>>>(a2buf, w2T, b2, out);
}